// Round 9
// baseline (11482.000 us; speedup 1.0000x reference)
//
#include <hip/hip_runtime.h>
#include <hip/hip_fp16.h>

#define BB 64
#define TT 2048
#define DD 256
#define HH 256
#define CHUNK 256
#define NCHUNK 8
#define PB 8          // batches per serial block

typedef _Float16 f16x8 __attribute__((ext_vector_type(8)));
typedef _Float16 f16x4 __attribute__((ext_vector_type(4)));
typedef _Float16 h2t   __attribute__((ext_vector_type(2)));
typedef float    f32x4 __attribute__((ext_vector_type(4)));
union V8 { f16x8 v; h2t p[4]; };

__device__ __forceinline__ float sigm(float v){ return __builtin_amdgcn_rcpf(1.f+__expf(-v)); }
__device__ __forceinline__ float tanh_f(float v){ float e=__expf(2.f*v); return 1.f-2.f*__builtin_amdgcn_rcpf(e+1.f); }

// Pack W [256][1024] f32 (k-major) into f16 layout [k/8][1024][8] (for the GEMM)
__global__ void pack_w(const float* __restrict__ w, _Float16* __restrict__ o) {
    int idx = blockIdx.x * 256 + threadIdx.x;
    int j = idx & 1023;
    int k = idx >> 10;
    o[(((k >> 3) * 1024) + j) * 8 + (k & 7)] = (_Float16)w[idx];
}

// gx = x @ W_xh + (b_xh + b_hh), layout gx[((b*CHUNK+tl)*256 + dim)*4 + gate] f16
__global__ __launch_bounds__(256) void gx_gemm(
    const float* __restrict__ x,
    const _Float16* __restrict__ Wx,   // packed [32][1024][8]
    const float* __restrict__ b_xh,
    const float* __restrict__ b_hh,
    _Float16* __restrict__ gx,
    int t0)
{
    __shared__ _Float16 xl[64 * 280];

    const int tid = threadIdx.x;
    const int nb = blockIdx.x;   // col block 0..15
    const int rb = blockIdx.y;   // row block 0..255

    for (int it = 0; it < 16; ++it) {
        int idx = it * 256 + tid;
        int row = idx >> 6, kq = idx & 63;
        int rlin = rb * 64 + row;
        int b = rlin >> 8, tl = rlin & 255;
        float4 v = *(const float4*)&x[((size_t)b * TT + (t0 + tl)) * DD + kq * 4];
        f16x4 h;
        h[0] = (_Float16)v.x; h[1] = (_Float16)v.y;
        h[2] = (_Float16)v.z; h[3] = (_Float16)v.w;
        *(f16x4*)&xl[row * 280 + kq * 4] = h;
    }
    __syncthreads();

    const int ty = tid >> 4, tx = tid & 15;
    const int col0 = nb * 64 + tx * 4;
    const int g0 = col0 >> 8, d0 = col0 & 255;
    const f16x8* __restrict__ wxp = (const f16x8*)Wx;

    float acc[4][4] = {};
#pragma unroll 2
    for (int kk = 0; kk < 32; ++kk) {
        V8 wv[4], xv[4];
#pragma unroll
        for (int c = 0; c < 4; ++c) wv[c].v = wxp[kk * 1024 + col0 + c];
#pragma unroll
        for (int r = 0; r < 4; ++r)
            xv[r].v = *(const f16x8*)&xl[(ty + 16 * r) * 280 + kk * 8];
#pragma unroll
        for (int r = 0; r < 4; ++r)
#pragma unroll
            for (int c = 0; c < 4; ++c)
#pragma unroll
                for (int q = 0; q < 4; ++q)
                    acc[r][c] = __builtin_amdgcn_fdot2(xv[r].p[q], wv[c].p[q], acc[r][c], false);
    }

    float bb[4];
#pragma unroll
    for (int c = 0; c < 4; ++c) bb[c] = b_xh[col0 + c] + b_hh[col0 + c];

#pragma unroll
    for (int r = 0; r < 4; ++r) {
        int rlin = rb * 64 + ty + 16 * r;
        int b = rlin >> 8, tl = rlin & 255;
#pragma unroll
        for (int c = 0; c < 4; ++c)
            gx[((size_t)(b * CHUNK + tl) * 256 + (d0 + c)) * 4 + g0] =
                (_Float16)(acc[r][c] + bb[c]);
    }
}

// swizzled A index: row-based XOR on the dim axis (16B granules)
#define AIDX(row, d) ((row) * 256 + ((d) ^ (((row) & 7) << 3)))

// ================= serial kernel macros =================
#define FOR_GDH(M) M(0,0) M(0,1) M(1,0) M(1,1) M(2,0) M(2,1) M(3,0) M(3,1)

#define DECLW(g,dh) f16x8 wf_##g##_##dh##_0, wf_##g##_##dh##_1, wf_##g##_##dh##_2, \
                          wf_##g##_##dh##_3, wf_##g##_##dh##_4, wf_##g##_##dh##_5;

#define LOADW1(g,dh,kt) { f16x8 t_; \
    _Pragma("unroll") \
    for (int e = 0; e < 8; ++e) \
        t_[e] = (_Float16)W_hh[(size_t)((kt)*32 + l4*8 + e)*1024 + (g)*256 + wbase + (dh)*16 + l15]; \
    wf_##g##_##dh##_##kt = t_; }

#define LOADW(g,dh) LOADW1(g,dh,0) LOADW1(g,dh,1) LOADW1(g,dh,2) \
                    LOADW1(g,dh,3) LOADW1(g,dh,4) LOADW1(g,dh,5)

#define KTR(kt,dh) { \
    f16x8 af_ = *(const f16x8*)&Apar[(l15 << 8) + ((((kt)*32) + l4*8) ^ aswz)]; \
    ac0_ = __builtin_amdgcn_mfma_f32_16x16x32_f16(af_, wf_0_##dh##_##kt, ac0_, 0,0,0); \
    ac1_ = __builtin_amdgcn_mfma_f32_16x16x32_f16(af_, wf_1_##dh##_##kt, ac1_, 0,0,0); \
    ac2_ = __builtin_amdgcn_mfma_f32_16x16x32_f16(af_, wf_2_##dh##_##kt, ac2_, 0,0,0); \
    ac3_ = __builtin_amdgcn_mfma_f32_16x16x32_f16(af_, wf_3_##dh##_##kt, ac3_, 0,0,0); }

// Wl read: cr = (kt-6)*4 + l4, col' = col ^ (cr&7)
#define BLD(g,dh,kt) (*(const f16x8*)&Wl[(size_t)((((kt)-6)*4 + l4)*1024 + \
    (((g)*256 + wbase + (dh)*16 + l15) ^ ((((kt)-6)*4 + l4) & 7)))*8])

#define KTL(kt,dh) { \
    f16x8 af_ = *(const f16x8*)&Apar[(l15 << 8) + ((((kt)*32) + l4*8) ^ aswz)]; \
    ac0_ = __builtin_amdgcn_mfma_f32_16x16x32_f16(af_, BLD(0,dh,kt), ac0_, 0,0,0); \
    ac1_ = __builtin_amdgcn_mfma_f32_16x16x32_f16(af_, BLD(1,dh,kt), ac1_, 0,0,0); \
    ac2_ = __builtin_amdgcn_mfma_f32_16x16x32_f16(af_, BLD(2,dh,kt), ac2_, 0,0,0); \
    ac3_ = __builtin_amdgcn_mfma_f32_16x16x32_f16(af_, BLD(3,dh,kt), ac3_, 0,0,0); }

#define UPD(j,dh) { \
    const int gb_ = blk*PB + 2*l4 + (j); \
    const int d_  = wbase + (dh)*16 + l15; \
    float h0n_ = 0.f, h1n_ = 0.f; \
    if (l0act) { \
        float gi_ = ac0_[2*(j)] + (float)gv##j##_##dh[0]; \
        float gf_ = ac1_[2*(j)] + (float)gv##j##_##dh[1]; \
        float gg_ = ac2_[2*(j)] + (float)gv##j##_##dh[2]; \
        float go_ = ac3_[2*(j)] + (float)gv##j##_##dh[3]; \
        c0s_##dh[j] = c0s_##dh[j]*sigm(gf_) + sigm(gi_)*tanh_f(gg_); \
        h0n_ = sigm(go_)*tanh_f(c0s_##dh[j]); \
    } \
    if (l1act) { \
        float gi_ = ac0_[2*(j)] + ac0_[2*(j)+1] + bhv_[0]; \
        float gf_ = ac1_[2*(j)] + ac1_[2*(j)+1] + bhv_[1]; \
        float gg_ = ac2_[2*(j)] + ac2_[2*(j)+1] + bhv_[2]; \
        float go_ = ac3_[2*(j)] + ac3_[2*(j)+1] + bhv_[3]; \
        c1s_##dh[j] = c1s_##dh[j]*sigm(gf_) + sigm(gi_)*tanh_f(gg_); \
        h1n_ = sigm(go_)*tanh_f(c1s_##dh[j]); \
    } \
    dv##j##dh = h1n_;   /* deferred global store (flushed next phase) */ \
    A[parx][AIDX((2*l4+(j))*2 + 0, d_)] = (_Float16)h0n_; \
    A[parx][AIDX((2*l4+(j))*2 + 1, d_)] = (_Float16)h1n_; \
    if (last) { \
        if (l0act && p == CHUNK-1) { out[FIN + gb_*256 + d_] = h0n_; out[FIN + 32768 + gb_*256 + d_] = c0s_##dh[j]; } \
        if (p == nph-1) { out[FIN + 16384 + gb_*256 + d_] = h1n_; out[FIN + 49152 + gb_*256 + d_] = c1s_##dh[j]; } \
    } else if (p == nph-1) { \
        st[gb_*256 + d_] = h0n_; st[16384 + gb_*256 + d_] = h1n_; \
        st[32768 + gb_*256 + d_] = c0s_##dh[j]; st[49152 + gb_*256 + d_] = c1s_##dh[j]; } }

#define HALF(dh) { \
    float4 bhv_ = *(const float4*)&bh2l[(wbase + (dh)*16 + l15)*4]; \
    f32x4 ac0_ = {}, ac1_ = {}, ac2_ = {}, ac3_ = {}; \
    KTR(0,dh) KTR(1,dh) KTR(2,dh) KTR(3,dh) KTR(4,dh) KTR(5,dh) \
    KTL(6,dh) KTL(7,dh) \
    UPD(0,dh) UPD(1,dh) }

#define STINIT(j,dh) { \
    int gb_ = blk*PB + 2*l4 + (j); \
    int d_  = wbase + (dh)*16 + l15; \
    float h0i_ = 0.f, h1i_ = 0.f; \
    if (!first) { \
        h0i_ = st[gb_*256 + d_]; h1i_ = st[16384 + gb_*256 + d_]; \
        c0s_##dh[j] = st[32768 + gb_*256 + d_]; c1s_##dh[j] = st[49152 + gb_*256 + d_]; \
    } \
    A[0][AIDX((2*l4+(j))*2 + 0, d_)] = (_Float16)h0i_; \
    A[0][AIDX((2*l4+(j))*2 + 1, d_)] = (_Float16)h1i_; }

// Serial recurrence: 8 blocks x 8 batches, 512 threads (8 waves, 2/SIMD).
// W_hh k in [0,192) in 192 named regs/wave; k in [192,256) in 128 KB LDS.
__global__ __launch_bounds__(512, 2) void lstm_serial(
    const float* __restrict__ W_hh,    // [256][1024] f32
    const float* __restrict__ b_hh,    // [1024]
    const _Float16* __restrict__ gx,   // [(b*CHUNK+tl)*256 + dim]*4 + gate (incl. b_xh+b_hh)
    float* __restrict__ out,
    float* __restrict__ st,            // h0,h1,c0,c1 each [64][256] f32
    int t0, int nph, int first, int last)
{
    __shared__ _Float16 A[2][16*256];      // 16 KB, XOR-swizzled rows
    __shared__ _Float16 Wl[8 * 1024 * 8];  // 128 KB: [cr][col^ (cr&7)][8]
    __shared__ float    bh2l[256*4];       // 4 KB: 2*b_hh as [dim][gate]

    const int tid = threadIdx.x;
    const int blk = blockIdx.x;
    const int l   = tid & 63;
    const int l15 = l & 15;
    const int l4  = l >> 4;
    const int wbase = (tid >> 6) * 32;
    const int aswz = (l15 & 7) << 3;

    // ---- stage LDS weights (k in [192,256)), col-swizzled per cr ----
    for (int v = tid; v < 8192; v += 512) {
        int cr = v >> 10, col = v & 1023;
        f16x8 t;
#pragma unroll
        for (int e = 0; e < 8; ++e)
            t[e] = (_Float16)W_hh[(size_t)(192 + cr * 8 + e) * 1024 + col];
        *(f16x8*)&Wl[(size_t)(cr * 1024 + (col ^ (cr & 7))) * 8] = t;
    }
    // ---- stage 2*b_hh table ----
    for (int i = tid; i < 1024; i += 512)
        bh2l[i] = 2.f * b_hh[(i & 3) * 256 + (i >> 2)];

    // ---- weight registers: k in [0,192), 48 named f16x8 ----
    FOR_GDH(DECLW)
    FOR_GDH(LOADW)

    // ---- state ----
    float c0s_0[2] = {0.f,0.f}, c0s_1[2] = {0.f,0.f};
    float c1s_0[2] = {0.f,0.f}, c1s_1[2] = {0.f,0.f};
    STINIT(0,0) STINIT(0,1) STINIT(1,0) STINIT(1,1)
    __syncthreads();

    const size_t FIN = (size_t)BB * TT * HH;
    const int gb0 = blk * PB + 2 * l4;
    const int dbase = wbase + l15;

    // pointer-incremented addressing
    float* outp0 = out + ((size_t)gb0 * TT + (t0 - 1 + (first ? 1 : 0))) * HH + dbase;
    float* outp1 = out + ((size_t)(gb0 + 1) * TT + (t0 - 1 + (first ? 1 : 0))) * HH + dbase;
    const _Float16* gxp0 = gx + ((size_t)gb0 * CHUNK * 256 + dbase) * 4;
    const _Float16* gxp1 = gx + ((size_t)(gb0 + 1) * CHUNK * 256 + dbase) * 4;

    float dv00 = 0.f, dv01 = 0.f, dv10 = 0.f, dv11 = 0.f;
    bool pv = false;

    for (int p = 0; p < nph; ++p) {
        const int par = p & 1, parx = par ^ 1;
        const bool l0act = (p < CHUNK);
        const bool l1act = !(first && p == 0);
        const _Float16* Apar = &A[par][0];

        // flush previous phase's h1 stores (ack hides under this phase)
        if (pv) {
            outp0[0]  = dv00;  outp0[16] = dv01;
            outp1[0]  = dv10;  outp1[16] = dv11;
            outp0 += HH; outp1 += HH;
        }

        // issue all gx loads at phase top (latency hides under MFMA+LDS)
        f16x4 gv0_0 = {}, gv0_1 = {}, gv1_0 = {}, gv1_1 = {};
        if (l0act) {
            gv0_0 = *(const f16x4*)(gxp0);
            gv0_1 = *(const f16x4*)(gxp0 + 64);
            gv1_0 = *(const f16x4*)(gxp1);
            gv1_1 = *(const f16x4*)(gxp1 + 64);
        }
        gxp0 += 1024; gxp1 += 1024;

        HALF(0)
        HALF(1)

        pv = l1act;
        __syncthreads();
    }

    // epilogue: flush last phase's h1
    if (pv) {
        outp0[0]  = dv00;  outp0[16] = dv01;
        outp1[0]  = dv10;  outp1[16] = dv11;
    }
}

extern "C" void kernel_launch(void* const* d_in, const int* in_sizes, int n_in,
                              void* d_out, int out_size, void* d_ws, size_t ws_size,
                              hipStream_t stream) {
    const float* x    = (const float*)d_in[0];
    const float* W_xh = (const float*)d_in[1];
    const float* b_xh = (const float*)d_in[2];
    const float* W_hh = (const float*)d_in[3];
    const float* b_hh = (const float*)d_in[4];
    float* out = (float*)d_out;

    char* ws = (char*)d_ws;
    _Float16* wxp = (_Float16*)(ws);                    // 512 KB packed W_xh
    float*    st  = (float*)(ws + (512 << 10));         // 256 KB carried state
    _Float16* gx  = (_Float16*)(ws + (768 << 10));      // 33.5 MB gx chunk

    pack_w<<<1024, 256, 0, stream>>>(W_xh, wxp);

    for (int c = 0; c < NCHUNK; ++c) {
        int t0 = c * CHUNK;
        gx_gemm<<<dim3(16, 256), 256, 0, stream>>>(x, wxp, b_xh, b_hh, gx, t0);
        lstm_serial<<<8, 512, 0, stream>>>(W_hh, b_hh, gx, out, st,
                                           t0, (c == NCHUNK - 1) ? CHUNK + 1 : CHUNK,
                                           c == 0, c == NCHUNK - 1);
    }
}

// Round 10
// 6880.434 us; speedup vs baseline: 1.6688x; 1.6688x over previous
//
#include <hip/hip_runtime.h>
#include <hip/hip_fp16.h>

#define BB 64
#define TT 2048
#define DD 256
#define HH 256
#define CHUNK 256
#define NCHUNK 8
#define PB 8          // batches per serial block
#define RS 264        // A-row stride (f16)
#define NSER 8        // serial blocks
#define GRID 240      // total persistent blocks (<=CU count, safety margin)

typedef _Float16 f16x8 __attribute__((ext_vector_type(8)));
typedef _Float16 f16x4 __attribute__((ext_vector_type(4)));
typedef _Float16 h2t   __attribute__((ext_vector_type(2)));
typedef float    f32x4 __attribute__((ext_vector_type(4)));
union V8 { f16x8 v; h2t p[4]; };

__device__ __forceinline__ float sigm(float v){ return __builtin_amdgcn_rcpf(1.f+__expf(-v)); }
__device__ __forceinline__ float tanh_f(float v){ float e=__expf(2.f*v); return 1.f-2.f*__builtin_amdgcn_rcpf(e+1.f); }

// Pack W [256][1024] f32 (k-major) into f16 layout [k/8][1024][8]
__global__ void pack_w(const float* __restrict__ w, _Float16* __restrict__ o) {
    int idx = blockIdx.x * 256 + threadIdx.x;
    int j = idx & 1023;
    int k = idx >> 10;
    o[(((k >> 3) * 1024) + j) * 8 + (k & 7)] = (_Float16)w[idx];
}

// ---- grid barrier: flat monotonic counter, device scope, fenced ----
__device__ __forceinline__ void gridbar(int* bar, int gen) {
    __syncthreads();
    if (threadIdx.x == 0) {
        __builtin_amdgcn_fence(__ATOMIC_RELEASE, "agent");   // flush my XCD L2 writes
        __hip_atomic_fetch_add(bar, 1, __ATOMIC_RELAXED, __HIP_MEMORY_SCOPE_AGENT);
        while (__hip_atomic_load(bar, __ATOMIC_RELAXED, __HIP_MEMORY_SCOPE_AGENT) < GRID * gen)
            __builtin_amdgcn_s_sleep(8);
        __builtin_amdgcn_fence(__ATOMIC_ACQUIRE, "agent");   // invalidate stale L1/L2 lines
    }
    __syncthreads();
}

union SMem {
    struct { _Float16 A[2 * 16 * RS]; _Float16 Wl[8 * 1024 * 8]; } s;  // 147,968 B
    _Float16 xl[64 * 280];                                             // 35,840 B
};

// gx = x @ W_xh + (b_xh + b_hh) for chunk c, grid-strided over gemm blocks.
__device__ void gemm_chunk(const float* __restrict__ x, const f16x8* __restrict__ wxp,
                           const float* __restrict__ b_xh, const float* __restrict__ b_hh,
                           _Float16* __restrict__ gxb, int c, _Float16* xl)
{
    const int tid = threadIdx.x;
    const int t0 = c << 8;
    for (int T = (int)blockIdx.x - NSER; T < 2048; T += (GRID - NSER)) {
        const int rb = T >> 3, nb = T & 7;
        for (int it = 0; it < 8; ++it) {
            int idx = it * 512 + tid, row = idx >> 6, kq = idx & 63;
            int rlin = rb * 64 + row, b = rlin >> 8, tl = rlin & 255;
            float4 v = *(const float4*)&x[((size_t)b * TT + t0 + tl) * DD + kq * 4];
            f16x4 h; h[0]=(_Float16)v.x; h[1]=(_Float16)v.y; h[2]=(_Float16)v.z; h[3]=(_Float16)v.w;
            *(f16x4*)&xl[row * 280 + kq * 4] = h;
        }
        __syncthreads();
        const int ty = tid >> 5, tx = tid & 31;
        const int col0 = nb * 128 + tx * 4;
        float acc[4][4] = {};
#pragma unroll 2
        for (int kk = 0; kk < 32; ++kk) {
            V8 wv[4], xv[4];
#pragma unroll
            for (int c2 = 0; c2 < 4; ++c2) wv[c2].v = wxp[kk * 1024 + col0 + c2];
#pragma unroll
            for (int r = 0; r < 4; ++r) xv[r].v = *(const f16x8*)&xl[(ty + 16 * r) * 280 + kk * 8];
#pragma unroll
            for (int r = 0; r < 4; ++r)
#pragma unroll
                for (int c2 = 0; c2 < 4; ++c2)
#pragma unroll
                    for (int q = 0; q < 4; ++q)
                        acc[r][c2] = __builtin_amdgcn_fdot2(xv[r].p[q], wv[c2].p[q], acc[r][c2], false);
        }
        __syncthreads();   // xl reads done before next tile's restage
        float bb[4];
#pragma unroll
        for (int c2 = 0; c2 < 4; ++c2) bb[c2] = b_xh[col0 + c2] + b_hh[col0 + c2];
        const int g0 = col0 >> 8, d0 = col0 & 255;
#pragma unroll
        for (int r = 0; r < 4; ++r) {
            int rlin = rb * 64 + ty + 16 * r, b = rlin >> 8, tl = rlin & 255;
#pragma unroll
            for (int c2 = 0; c2 < 4; ++c2)
                gxb[((size_t)(b * CHUNK + tl) * 256 + d0 + c2) * 4 + g0] =
                    (_Float16)(acc[r][c2] + bb[c2]);
        }
    }
}

// ================= serial macros (r8 verbatim, pointer-based A) =================
#define FOR_GDH(M) M(0,0) M(0,1) M(1,0) M(1,1) M(2,0) M(2,1) M(3,0) M(3,1)

#define DECLW(g,dh) f16x8 wf_##g##_##dh##_0, wf_##g##_##dh##_1, wf_##g##_##dh##_2, \
                          wf_##g##_##dh##_3, wf_##g##_##dh##_4, wf_##g##_##dh##_5;

#define LOADW1(g,dh,kt) { f16x8 t_; \
    _Pragma("unroll") \
    for (int e = 0; e < 8; ++e) \
        t_[e] = (_Float16)W_hh[(size_t)((kt)*32 + l4*8 + e)*1024 + (g)*256 + wbase + (dh)*16 + l15]; \
    wf_##g##_##dh##_##kt = t_; }

#define LOADW(g,dh) LOADW1(g,dh,0) LOADW1(g,dh,1) LOADW1(g,dh,2) \
                    LOADW1(g,dh,3) LOADW1(g,dh,4) LOADW1(g,dh,5)

#define KTR(kt,dh) { f16x8 af_ = *(const f16x8*)&Ab[(kt)*32 + l4*8]; \
    ac0_ = __builtin_amdgcn_mfma_f32_16x16x32_f16(af_, wf_0_##dh##_##kt, ac0_, 0,0,0); \
    ac1_ = __builtin_amdgcn_mfma_f32_16x16x32_f16(af_, wf_1_##dh##_##kt, ac1_, 0,0,0); \
    ac2_ = __builtin_amdgcn_mfma_f32_16x16x32_f16(af_, wf_2_##dh##_##kt, ac2_, 0,0,0); \
    ac3_ = __builtin_amdgcn_mfma_f32_16x16x32_f16(af_, wf_3_##dh##_##kt, ac3_, 0,0,0); }

#define BLD(g,dh,kt) (*(const f16x8*)&Wl[(size_t)((((kt)-6)*4 + l4)*1024 + (g)*256 + wbase + (dh)*16 + l15)*8])

#define KTL(kt,dh) { f16x8 af_ = *(const f16x8*)&Ab[(kt)*32 + l4*8]; \
    ac0_ = __builtin_amdgcn_mfma_f32_16x16x32_f16(af_, BLD(0,dh,kt), ac0_, 0,0,0); \
    ac1_ = __builtin_amdgcn_mfma_f32_16x16x32_f16(af_, BLD(1,dh,kt), ac1_, 0,0,0); \
    ac2_ = __builtin_amdgcn_mfma_f32_16x16x32_f16(af_, BLD(2,dh,kt), ac2_, 0,0,0); \
    ac3_ = __builtin_amdgcn_mfma_f32_16x16x32_f16(af_, BLD(3,dh,kt), ac3_, 0,0,0); }

#define UPD(j,dh) { \
    const int gb_ = blk*PB + 2*l4 + (j); \
    const int d_  = wbase + (dh)*16 + l15; \
    float h0n_ = 0.f, h1n_ = 0.f; \
    if (l0act) { \
        float gi_ = ac0_[2*(j)] + (float)gv##j##_[0]; \
        float gf_ = ac1_[2*(j)] + (float)gv##j##_[1]; \
        float gg_ = ac2_[2*(j)] + (float)gv##j##_[2]; \
        float go_ = ac3_[2*(j)] + (float)gv##j##_[3]; \
        c0s_##dh[j] = c0s_##dh[j]*sigm(gf_) + sigm(gi_)*tanh_f(gg_); \
        h0n_ = sigm(go_)*tanh_f(c0s_##dh[j]); \
    } \
    if (l1act) { \
        float gi_ = ac0_[2*(j)] + ac0_[2*(j)+1] + bh2_##dh##_0; \
        float gf_ = ac1_[2*(j)] + ac1_[2*(j)+1] + bh2_##dh##_1; \
        float gg_ = ac2_[2*(j)] + ac2_[2*(j)+1] + bh2_##dh##_2; \
        float go_ = ac3_[2*(j)] + ac3_[2*(j)+1] + bh2_##dh##_3; \
        c1s_##dh[j] = c1s_##dh[j]*sigm(gf_) + sigm(gi_)*tanh_f(gg_); \
        h1n_ = sigm(go_)*tanh_f(c1s_##dh[j]); \
        out[((size_t)gb_*TT + (t0 + p - 1))*HH + d_] = h1n_; \
    } \
    A[(parx*16 + (2*l4+(j))*2 + 0)*RS + d_] = (_Float16)h0n_; \
    A[(parx*16 + (2*l4+(j))*2 + 1)*RS + d_] = (_Float16)h1n_; \
    if (lastc) { \
        if (l0act && p == CHUNK-1) { out[FIN + gb_*256 + d_] = h0n_; out[FIN + 32768 + gb_*256 + d_] = c0s_##dh[j]; } \
        if (p == nph-1) { out[FIN + 16384 + gb_*256 + d_] = h1n_; out[FIN + 49152 + gb_*256 + d_] = c1s_##dh[j]; } \
    } }

#define HALF(dh) { \
    f16x4 gv0_ = {}, gv1_ = {}; \
    if (l0act) { \
        gv0_ = *(const f16x4*)&gxc[((size_t)((blk*PB + 2*l4 + 0)*CHUNK + p)*256 + wbase + (dh)*16 + l15)*4]; \
        gv1_ = *(const f16x4*)&gxc[((size_t)((blk*PB + 2*l4 + 1)*CHUNK + p)*256 + wbase + (dh)*16 + l15)*4]; \
    } \
    f32x4 ac0_ = {}, ac1_ = {}, ac2_ = {}, ac3_ = {}; \
    KTR(0,dh) KTR(1,dh) KTR(2,dh) KTR(3,dh) KTR(4,dh) KTR(5,dh) \
    KTL(6,dh) KTL(7,dh) \
    UPD(0,dh) UPD(1,dh) }

// Persistent fused kernel: blocks 0..7 = serial recurrence (all chunks),
// blocks 8..GRID-1 = gx GEMM for chunk c+1 overlapped with serial chunk c.
__global__ __launch_bounds__(512, 2) void lstm_coop(
    const float* __restrict__ x,
    const _Float16* __restrict__ wxp16,
    const float* __restrict__ b_xh, const float* __restrict__ b_hh,
    const float* __restrict__ W_hh,
    float* __restrict__ out,
    _Float16* __restrict__ gx0, _Float16* __restrict__ gx1,
    int* __restrict__ bar, int overlap)
{
    __shared__ SMem sm;
    const int tid = threadIdx.x;
    const f16x8* wxp = (const f16x8*)wxp16;

    if (blockIdx.x < NSER) {
        // ================= serial path =================
        _Float16* A  = sm.s.A;
        _Float16* Wl = sm.s.Wl;
        const int blk = blockIdx.x;
        const int l   = tid & 63;
        const int l15 = l & 15;
        const int l4  = l >> 4;
        const int wbase = (tid >> 6) * 32;

        // LDS weights: k in [192,256)
        for (int v = tid; v < 8192; v += 512) {
            int cr = v >> 10, col = v & 1023;
            f16x8 t;
#pragma unroll
            for (int e = 0; e < 8; ++e)
                t[e] = (_Float16)W_hh[(size_t)(192 + cr * 8 + e) * 1024 + col];
            *(f16x8*)&Wl[(size_t)v * 8] = t;
        }
        // register weights: k in [0,192), 48 named f16x8
        FOR_GDH(DECLW)
        FOR_GDH(LOADW)

        float bh2_0_0 = 2.f*b_hh[0*256 + wbase + l15],      bh2_0_1 = 2.f*b_hh[1*256 + wbase + l15];
        float bh2_0_2 = 2.f*b_hh[2*256 + wbase + l15],      bh2_0_3 = 2.f*b_hh[3*256 + wbase + l15];
        float bh2_1_0 = 2.f*b_hh[0*256 + wbase + 16 + l15], bh2_1_1 = 2.f*b_hh[1*256 + wbase + 16 + l15];
        float bh2_1_2 = 2.f*b_hh[2*256 + wbase + 16 + l15], bh2_1_3 = 2.f*b_hh[3*256 + wbase + 16 + l15];

        float c0s_0[2]={0.f,0.f}, c0s_1[2]={0.f,0.f};
        float c1s_0[2]={0.f,0.f}, c1s_1[2]={0.f,0.f};
        for (int i = tid; i < 16 * RS; i += 512) A[i] = (_Float16)0;   // parity-0 A = zeros

        int gen = 0;
        gridbar(bar, ++gen);                 // wait for chunk-0 gx

        const size_t FIN = (size_t)BB * TT * HH;
        for (int c = 0; c < NCHUNK; ++c) {
            const _Float16* gxc = (c & 1) ? gx1 : gx0;   // gx1==gx0 in non-overlap mode
            const int t0 = c << 8;
            const int nph = (c == NCHUNK - 1) ? CHUNK + 1 : CHUNK;
            const bool lastc = (c == NCHUNK - 1);
            for (int p = 0; p < nph; ++p) {
                const int par = p & 1, parx = par ^ 1;
                const bool l0act = (p < CHUNK);
                const bool l1act = (c > 0) || (p > 0);
                const _Float16* Ab = A + (par * 16 + l15) * RS;
                HALF(0)
                HALF(1)
                if (p + 1 < nph) __syncthreads();
            }
            if (c < NCHUNK - 1) {
                gridbar(bar, ++gen);                       // release gx buffer / sync
                if (!overlap) gridbar(bar, ++gen);         // wait for next chunk's gx
            }
        }
    } else {
        // ================= gemm path =================
        gemm_chunk(x, wxp, b_xh, b_hh, gx0, 0, sm.xl);     // prologue: chunk 0
        int gen = 0;
        gridbar(bar, ++gen);
        for (int c = 0; c < NCHUNK - 1; ++c) {
            if (overlap) {
                gemm_chunk(x, wxp, b_xh, b_hh, ((c + 1) & 1) ? gx1 : gx0, c + 1, sm.xl);
                gridbar(bar, ++gen);
            } else {
                gridbar(bar, ++gen);                       // wait serial release of gx0
                gemm_chunk(x, wxp, b_xh, b_hh, gx0, c + 1, sm.xl);
                gridbar(bar, ++gen);                       // signal ready
            }
        }
    }
}

extern "C" void kernel_launch(void* const* d_in, const int* in_sizes, int n_in,
                              void* d_out, int out_size, void* d_ws, size_t ws_size,
                              hipStream_t stream) {
    const float* x    = (const float*)d_in[0];
    const float* W_xh = (const float*)d_in[1];
    const float* b_xh = (const float*)d_in[2];
    const float* W_hh = (const float*)d_in[3];
    const float* b_hh = (const float*)d_in[4];
    float* out = (float*)d_out;

    char* ws = (char*)d_ws;
    _Float16* wxp = (_Float16*)ws;                          // 512 KB packed W_xh
    int* bar      = (int*)(ws + (512 << 10));               // 4 B barrier counter
    char* gxbase  = ws + (512 << 10) + 256;
    const size_t gxb = (size_t)64 * 256 * 1024 * 2;         // 33.55 MB per gx buffer
    _Float16* gx0 = (_Float16*)gxbase;
    int overlap = (ws_size >= (size_t)(512 << 10) + 256 + 2 * gxb) ? 1 : 0;
    _Float16* gx1 = overlap ? (_Float16*)(gxbase + gxb) : gx0;

    pack_w<<<1024, 256, 0, stream>>>(W_xh, wxp);
    hipMemsetAsync(bar, 0, 4, stream);
    lstm_coop<<<GRID, 512, 0, stream>>>(x, wxp, b_xh, b_hh, W_hh, out, gx0, gx1, bar, overlap);
}